// Round 7
// baseline (10.601 us; speedup 1.0000x reference)
//
#include <hip/hip_runtime.h>

// POS extractor, algebraically collapsed + prefix-sum sliding windows.
// Round-6: R3 structure (best measured) with paired float2/b64 LDS reads in
// the window-coefficient and output phases, and fast rcp/rsq/sqrt intrinsics
// (precision proven in R5: absmax identical to IEEE path).
//
//   h[b,w,l] = A_w*x0[t] + B_w*x1[t] + C_w*x2[t]   (t = w+l)
//   H[b,n]   = x0[n]*SA[n] + x1[n]*SB[n] + x2[n]*SC[n],
//              SA[n] = sum_{w in [n-47,n] ∩ [0,W)} A_w  (etc.)

constexpr int L_WIN = 48;                     // int(30*1.6)
constexpr int CHUNK = 512;                    // outputs per block
constexpr int NSAMP = CHUNK + 2 * L_WIN - 2;  // 606 staged samples
constexpr int NWIN  = CHUNK + L_WIN - 1;      // 559 windows per block
constexpr int BLOCK = 576;                    // 9 waves -> one per Q array
constexpr int QLEN  = NSAMP + 1;              // 607 prefix entries
constexpr int QPAD  = 640;                    // even -> float2-aligned rows
constexpr int PLEN  = NWIN + 1;               // 560 prefix entries
constexpr int PPAD  = 576;                    // even -> float2-aligned rows

// In-place exclusive-style prefix scan of a[0..len) by ONE full wave.
// 10 consecutive elements per lane in regs, then 6-step shfl wave scan.
__device__ __forceinline__ void wave_scan_inplace(float* a, int len) {
    const int lane = threadIdx.x & 63;
    const int base = lane * 10;
    float r[10];
    float run = 0.0f;
    #pragma unroll
    for (int j = 0; j < 10; ++j) {
        const int e = base + j;
        const float v = (e < len) ? a[e] : 0.0f;
        run += v;
        r[j] = run;                 // inclusive within lane
    }
    float incl = run;               // wave-level inclusive scan of lane sums
    #pragma unroll
    for (int d = 1; d < 64; d <<= 1) {
        const float v = __shfl_up(incl, d);
        if (lane >= d) incl += v;
    }
    const float excl = incl - run;
    #pragma unroll
    for (int j = 0; j < 10; ++j) {
        const int e = base + j;
        if (e < len) a[e] = excl + r[j];
    }
}

// Window coefficients from the 9 cross-moments (m_i ~ 48, well-conditioned
// for v_rcp; rel-err ~1e-6 vs threshold 1.71).
__device__ __forceinline__ void pos_coeffs(
    float m0, float m1, float m2,
    float p00, float p11, float p22,
    float p01, float p02, float p12,
    float& A, float& B, float& C)
{
    const float q0 = (float)L_WIN * __builtin_amdgcn_rcpf(m0);
    const float q1 = (float)L_WIN * __builtin_amdgcn_rcpf(m1);
    const float q2 = (float)L_WIN * __builtin_amdgcn_rcpf(m2);
    // sum S0^2 = sum (Cn1 - Cn2)^2
    float ss0 = p11 * q1 * q1 - 2.f * p12 * q1 * q2 + p22 * q2 * q2;
    // sum S1^2 = sum (-2 Cn0 + Cn1 + Cn2)^2
    float ss1 = 4.f * p00 * q0 * q0 + p11 * q1 * q1 + p22 * q2 * q2
              - 4.f * p01 * q0 * q1 - 4.f * p02 * q0 * q2
              + 2.f * p12 * q1 * q2;
    ss0 = fmaxf(ss0, 0.0f);
    const float alpha = __builtin_amdgcn_sqrtf(ss0) *
                        __builtin_amdgcn_rsqf(ss1);   // ddof divisor cancels
    A = -2.0f * alpha * q0;
    B = (1.0f + alpha) * q1;
    C = (alpha - 1.0f) * q2;
}

__global__ __launch_bounds__(BLOCK)
void pos_kernel(const float* __restrict__ x, float* __restrict__ out,
                int B, int N) {
    const int W  = N - L_WIN;              // 8144 valid windows
    const int b  = blockIdx.y;
    const int n0 = blockIdx.x * CHUNK;
    const int t0 = n0 - (L_WIN - 1);       // first staged sample (may be <0)
    const int w0 = t0;                     // first window index  (may be <0)

    // Q[k] : exclusive prefix of product k over staged samples
    //   k = 0..2 : x0, x1, x2 ; 3..5 : squares ; 6..8 : cross products
    __shared__ float Q[9][QPAD];
    __shared__ float PC[3][PPAD];          // exclusive prefix of coeffs A,B,C

    const float* gx = x + (size_t)b * N * 3;
    const int tid  = threadIdx.x;
    const int wid  = tid >> 6;

    // ---- phase A: coalesced loads -> 9 per-sample products -> LDS ----
    for (int i = tid; i < NSAMP; i += BLOCK) {
        const int t = t0 + i;
        float x0 = 0.0f, x1 = 0.0f, x2 = 0.0f;
        if (t >= 0 && t < N) {             // OOB samples only feed invalid
            const float* p = gx + (size_t)3 * t;   // windows (coeffs forced 0)
            x0 = p[0]; x1 = p[1]; x2 = p[2];
        }
        Q[0][i + 1] = x0;       Q[1][i + 1] = x1;       Q[2][i + 1] = x2;
        Q[3][i + 1] = x0 * x0;  Q[4][i + 1] = x1 * x1;  Q[5][i + 1] = x2 * x2;
        Q[6][i + 1] = x0 * x1;  Q[7][i + 1] = x0 * x2;  Q[8][i + 1] = x1 * x2;
    }
    if (tid < 9) Q[tid][0] = 0.0f;
    __syncthreads();

    // ---- phase B: 9 prefix scans, one wave each ----
    wave_scan_inplace(&Q[wid][0], QLEN);   // wid in [0,9)
    __syncthreads();

    // ---- phase C: window coefficients, 2 windows/thread, b64 LDS reads ----
    if (tid < (NWIN + 1) / 2) {            // 280 threads
        const int wl0 = 2 * tid;           // even -> 8B-aligned float2 reads
        float d0[9], d1[9];
        #pragma unroll
        for (int k = 0; k < 9; ++k) {
            const float2 lo = *reinterpret_cast<const float2*>(&Q[k][wl0]);
            const float2 hi = *reinterpret_cast<const float2*>(&Q[k][wl0 + L_WIN]);
            d0[k] = hi.x - lo.x;           // moments of window wl0
            d1[k] = hi.y - lo.y;           // moments of window wl0+1
        }
        {
            const int w = w0 + wl0;
            float A = 0.f, Bc = 0.f, C = 0.f;
            if (w >= 0 && w < W)
                pos_coeffs(d0[0], d0[1], d0[2], d0[3], d0[4], d0[5],
                           d0[6], d0[7], d0[8], A, Bc, C);
            PC[0][wl0 + 1] = A;
            PC[1][wl0 + 1] = Bc;
            PC[2][wl0 + 1] = C;
        }
        if (wl0 + 1 < NWIN) {
            const int w = w0 + wl0 + 1;
            float A = 0.f, Bc = 0.f, C = 0.f;
            if (w >= 0 && w < W)
                pos_coeffs(d1[0], d1[1], d1[2], d1[3], d1[4], d1[5],
                           d1[6], d1[7], d1[8], A, Bc, C);
            PC[0][wl0 + 2] = A;
            PC[1][wl0 + 2] = Bc;
            PC[2][wl0 + 2] = C;
        }
    }
    if (tid < 3) PC[tid][0] = 0.0f;
    __syncthreads();

    // ---- phase D: 3 prefix scans of coefficient arrays ----
    if (wid < 3) wave_scan_inplace(&PC[wid][0], PLEN);
    __syncthreads();

    // ---- phase E: 2 outputs/thread, b64 LDS + float2 global traffic ----
    if (tid < CHUNK / 2) {                 // 256 threads
        const int nl = 2 * tid;            // even -> all pairs 8B-aligned
        const int n  = n0 + nl;
        const float2 a0 = *reinterpret_cast<const float2*>(&PC[0][nl]);
        const float2 a1 = *reinterpret_cast<const float2*>(&PC[0][nl + L_WIN]);
        const float2 b0 = *reinterpret_cast<const float2*>(&PC[1][nl]);
        const float2 b1 = *reinterpret_cast<const float2*>(&PC[1][nl + L_WIN]);
        const float2 c0 = *reinterpret_cast<const float2*>(&PC[2][nl]);
        const float2 c1 = *reinterpret_cast<const float2*>(&PC[2][nl + L_WIN]);
        const float* p = gx + (size_t)3 * n;        // 12n bytes, n even -> 8B ok
        const float2 v0 = *reinterpret_cast<const float2*>(p);      // x0,x1 @n
        const float2 v1 = *reinterpret_cast<const float2*>(p + 2);  // x2@n, x0@n+1
        const float2 v2 = *reinterpret_cast<const float2*>(p + 4);  // x1,x2 @n+1
        float2 o;
        o.x = v0.x * (a1.x - a0.x) + v0.y * (b1.x - b0.x) + v1.x * (c1.x - c0.x);
        o.y = v1.y * (a1.y - a0.y) + v2.x * (b1.y - b0.y) + v2.y * (c1.y - c0.y);
        *reinterpret_cast<float2*>(&out[(size_t)b * N + n]) = o;
    }
}

extern "C" void kernel_launch(void* const* d_in, const int* in_sizes, int n_in,
                              void* d_out, int out_size, void* d_ws, size_t ws_size,
                              hipStream_t stream) {
    const float* x = (const float*)d_in[0];
    float* out = (float*)d_out;
    const int B = 32;
    const int N = in_sizes[0] / (B * 3);   // 8192
    dim3 grid(N / CHUNK, B);               // 16 x 32 = 512 blocks, 2/CU
    pos_kernel<<<grid, BLOCK, 0, stream>>>(x, out, B, N);
}

// Round 8
// 9.655 us; speedup vs baseline: 1.0980x; 1.0980x over previous
//
#include <hip/hip_runtime.h>

// POS extractor, algebraically collapsed + prefix-sum sliding windows.
// Round-7: REVERT to the round-3 kernel verbatim — best measured (9.63 us).
// R4 (barrier fusion, uncoalesced loads): 12.66. R5 (4 blocks/CU, fast-math):
// 10.02. R6 (float2 LDS reads, 2 items/thread): 10.60. All structural
// variants land at 9.6-12.7 us => dispatch/replay floor dominates; this is
// the best-measured configuration.
//
//   h[b,w,l] = A_w*x0[t] + B_w*x1[t] + C_w*x2[t]   (t = w+l)
//   H[b,n]   = x0[n]*SA[n] + x1[n]*SB[n] + x2[n]*SC[n],
//              SA[n] = sum_{w in [n-47,n] ∩ [0,W)} A_w  (etc.)
//
// Window coefficients from 9 cross-moments (sums of x_i and x_i*x_j over the
// 48-sample window), each moment computed as a difference of two prefix-sum
// reads. Coefficient sliding sums likewise via a second prefix pass.
// Mean-subtraction terms of the reference are analytically zero.

constexpr int L_WIN = 48;                     // int(30*1.6)
constexpr int CHUNK = 512;                    // outputs per block
constexpr int NSAMP = CHUNK + 2 * L_WIN - 2;  // 606 staged samples
constexpr int NWIN  = CHUNK + L_WIN - 1;      // 559 windows per block
constexpr int BLOCK = 576;                    // 9 waves -> one per Q array
constexpr int QLEN  = NSAMP + 1;              // 607 prefix entries
constexpr int QPAD  = 640;                    // 64 lanes * 10 elems
constexpr int PLEN  = NWIN + 1;               // 560 prefix entries
constexpr int PPAD  = 576;

// In-place exclusive-style prefix scan of a[0..len) by ONE full wave.
// Each lane owns 10 consecutive elements (sequential scan in regs), then a
// 6-step shfl_up wave scan combines lane totals. No cross-wave traffic.
__device__ __forceinline__ void wave_scan_inplace(float* a, int len) {
    const int lane = threadIdx.x & 63;
    const int base = lane * 10;
    float r[10];
    float run = 0.0f;
    #pragma unroll
    for (int j = 0; j < 10; ++j) {
        const int e = base + j;
        const float v = (e < len) ? a[e] : 0.0f;
        run += v;
        r[j] = run;                 // inclusive within lane
    }
    float incl = run;               // wave-level inclusive scan of lane sums
    #pragma unroll
    for (int d = 1; d < 64; d <<= 1) {
        const float v = __shfl_up(incl, d);
        if (lane >= d) incl += v;
    }
    const float excl = incl - run;  // sum of all lower lanes
    #pragma unroll
    for (int j = 0; j < 10; ++j) {
        const int e = base + j;
        if (e < len) a[e] = excl + r[j];
    }
}

__global__ __launch_bounds__(BLOCK)
void pos_kernel(const float* __restrict__ x, float* __restrict__ out,
                int B, int N) {
    const int W  = N - L_WIN;              // 8144 valid windows
    const int b  = blockIdx.y;
    const int n0 = blockIdx.x * CHUNK;
    const int t0 = n0 - (L_WIN - 1);       // first staged sample (may be <0)
    const int w0 = t0;                     // first window index  (may be <0)

    // Q[k][j] : after scan, exclusive prefix of product k over staged samples
    //   k = 0..2 : x0, x1, x2
    //   k = 3..5 : x0^2, x1^2, x2^2
    //   k = 6..8 : x0*x1, x0*x2, x1*x2
    __shared__ float Q[9][QPAD];
    __shared__ float PC[3][PPAD];          // prefix of window coeffs A,B,C

    const float* gx = x + (size_t)b * N * 3;
    const int tid = threadIdx.x;
    const int wid = tid >> 6;

    // ---- phase A: per-sample products -> LDS (coalesced global reads) ----
    for (int i = tid; i < NSAMP; i += BLOCK) {
        const int t = t0 + i;
        float x0 = 0.0f, x1 = 0.0f, x2 = 0.0f;
        if (t >= 0 && t < N) {             // OOB samples only feed invalid
            const float* p = gx + (size_t)3 * t;   // windows (coeffs forced 0)
            x0 = p[0]; x1 = p[1]; x2 = p[2];
        }
        Q[0][i + 1] = x0;       Q[1][i + 1] = x1;       Q[2][i + 1] = x2;
        Q[3][i + 1] = x0 * x0;  Q[4][i + 1] = x1 * x1;  Q[5][i + 1] = x2 * x2;
        Q[6][i + 1] = x0 * x1;  Q[7][i + 1] = x0 * x2;  Q[8][i + 1] = x1 * x2;
    }
    if (tid < 9) Q[tid][0] = 0.0f;
    __syncthreads();

    // ---- phase B: 9 prefix scans, one wave each ----
    wave_scan_inplace(&Q[wid][0], QLEN);   // wid in [0,9)
    __syncthreads();

    // ---- phase C: window coefficients (O(1) per window) ----
    for (int wl = tid; wl < NWIN; wl += BLOCK) {
        const int w = w0 + wl;
        float Ac = 0.0f, Bc = 0.0f, Cc = 0.0f;
        if (w >= 0 && w < W) {
            const float m0  = Q[0][wl + L_WIN] - Q[0][wl];
            const float m1  = Q[1][wl + L_WIN] - Q[1][wl];
            const float m2  = Q[2][wl + L_WIN] - Q[2][wl];
            const float p00 = Q[3][wl + L_WIN] - Q[3][wl];
            const float p11 = Q[4][wl + L_WIN] - Q[4][wl];
            const float p22 = Q[5][wl + L_WIN] - Q[5][wl];
            const float p01 = Q[6][wl + L_WIN] - Q[6][wl];
            const float p02 = Q[7][wl + L_WIN] - Q[7][wl];
            const float p12 = Q[8][wl + L_WIN] - Q[8][wl];
            const float q0 = (float)L_WIN / m0;    // 1/mean per channel
            const float q1 = (float)L_WIN / m1;
            const float q2 = (float)L_WIN / m2;
            // sum S0^2 = sum (Cn1 - Cn2)^2
            float ss0 = p11 * q1 * q1 - 2.f * p12 * q1 * q2 + p22 * q2 * q2;
            // sum S1^2 = sum (-2 Cn0 + Cn1 + Cn2)^2
            float ss1 = 4.f * p00 * q0 * q0 + p11 * q1 * q1 + p22 * q2 * q2
                      - 4.f * p01 * q0 * q1 - 4.f * p02 * q0 * q2
                      + 2.f * p12 * q1 * q2;
            ss0 = fmaxf(ss0, 0.0f);
            const float alpha = sqrtf(ss0 / ss1);  // ddof divisor cancels
            Ac = -2.0f * alpha * q0;
            Bc = (1.0f + alpha) * q1;
            Cc = (alpha - 1.0f) * q2;
        }
        PC[0][wl + 1] = Ac;
        PC[1][wl + 1] = Bc;
        PC[2][wl + 1] = Cc;
    }
    if (tid < 3) PC[tid][0] = 0.0f;
    __syncthreads();

    // ---- phase D: 3 prefix scans of the coefficient arrays ----
    if (wid < 3) wave_scan_inplace(&PC[wid][0], PLEN);
    __syncthreads();

    // ---- phase E: outputs (O(1) per output) ----
    for (int nl = tid; nl < CHUNK; nl += BLOCK) {
        const int n = n0 + nl;
        const float SA = PC[0][nl + L_WIN] - PC[0][nl];
        const float SB = PC[1][nl + L_WIN] - PC[1][nl];
        const float SC = PC[2][nl + L_WIN] - PC[2][nl];
        const float* p = gx + (size_t)3 * n;       // L1/L2-warm from phase A
        out[(size_t)b * N + n] = p[0] * SA + p[1] * SB + p[2] * SC;
    }
}

extern "C" void kernel_launch(void* const* d_in, const int* in_sizes, int n_in,
                              void* d_out, int out_size, void* d_ws, size_t ws_size,
                              hipStream_t stream) {
    const float* x = (const float*)d_in[0];
    float* out = (float*)d_out;
    const int B = 32;
    const int N = in_sizes[0] / (B * 3);   // 8192
    dim3 grid(N / CHUNK, B);               // 16 x 32 = 512 blocks
    pos_kernel<<<grid, BLOCK, 0, stream>>>(x, out, B, N);
}